// Round 6
// baseline (255.311 us; speedup 1.0000x reference)
//
#include <hip/hip_runtime.h>
#include <math.h>

#define B_  2
#define T_  12
#define N_  2048
#define D_  64
#define DI_ 128
#define DS_ 8
#define NM_ 10
#define CK_ 3
#define CS_ 2
#define TC_ 5
#define TT_ 17
#define L_  (T_*N_)        // 24576
#define CHUNK_ 64
#define NCH_ (L_/CHUNK_)   // 384

// ---------------- K0: fold small weight products ----------------
__global__ void k0_precomp(const float* __restrict__ msam_Wq, const float* __restrict__ msam_Mk,
                           const float* __restrict__ mem_Wq, const float* __restrict__ mem_M,
                           const float* __restrict__ mem_Wo,
                           float* __restrict__ W1, float* __restrict__ W1m, float* __restrict__ W2m) {
  int d = threadIdx.x;
  if (d >= 64) return;
  for (int m = 0; m < NM_; ++m) {
    float a = 0.f;
    for (int j = 0; j < 4; ++j) a += msam_Wq[d*4+j] * msam_Mk[m*4+j];
    W1[d*10+m] = a;
    float b = 0.f;
    for (int k = 0; k < 64; ++k) b += mem_Wq[d*64+k] * mem_M[m*64+k];
    W1m[d*10+m] = b;
    float c = 0.f;
    for (int k = 0; k < 64; ++k) c += mem_M[m*64+k] * mem_Wo[k*64+d];
    W2m[m*64+d] = c;
  }
}

// ---------------- K1a: msam conv as tiled fp32 GEMM ----------------
__global__ __launch_bounds__(256) void k1a_conv(const float* __restrict__ x,
    const float* __restrict__ cw, const float* __restrict__ cb,
    float* __restrict__ conv_raw) {
  __shared__ float ats[64*65];
  __shared__ float bts[192*64];
  int tid = threadIdx.x;
  int n0 = blockIdx.x * 64;
  int tc = blockIdx.y;
  int b  = blockIdx.z;
  for (int i = tid; i < 3072; i += 256)
    ((float4*)bts)[i] = ((const float4*)cw)[i];
  int ty = tid >> 4, tx = tid & 15;
  float acc[4][4] = {};
  for (int kk = 0; kk < 3; ++kk) {
    __syncthreads();
    const float* xs = x + (((size_t)b*T_ + (2*tc+kk))*N_ + n0)*64;
    for (int i = tid; i < 1024; i += 256) {
      int r = i >> 4, c = (i & 15) * 4;
      float4 v = ((const float4*)xs)[i];
      ats[r*65+c+0]=v.x; ats[r*65+c+1]=v.y; ats[r*65+c+2]=v.z; ats[r*65+c+3]=v.w;
    }
    __syncthreads();
    for (int k = 0; k < 64; ++k) {
      float a0 = ats[(ty*4+0)*65 + k];
      float a1 = ats[(ty*4+1)*65 + k];
      float a2 = ats[(ty*4+2)*65 + k];
      float a3 = ats[(ty*4+3)*65 + k];
      float4 bv = *(float4*)&bts[(kk*64+k)*64 + tx*4];
      acc[0][0]+=a0*bv.x; acc[0][1]+=a0*bv.y; acc[0][2]+=a0*bv.z; acc[0][3]+=a0*bv.w;
      acc[1][0]+=a1*bv.x; acc[1][1]+=a1*bv.y; acc[1][2]+=a1*bv.z; acc[1][3]+=a1*bv.w;
      acc[2][0]+=a2*bv.x; acc[2][1]+=a2*bv.y; acc[2][2]+=a2*bv.z; acc[2][3]+=a2*bv.w;
      acc[3][0]+=a3*bv.x; acc[3][1]+=a3*bv.y; acc[3][2]+=a3*bv.z; acc[3][3]+=a3*bv.w;
    }
  }
  float4 cbv = *(const float4*)&cb[tx*4];
  size_t rowbase = ((size_t)b*TC_ + tc)*N_ + n0;
  #pragma unroll
  for (int i = 0; i < 4; ++i) {
    float4 o;
    o.x = acc[i][0]+cbv.x; o.y = acc[i][1]+cbv.y; o.z = acc[i][2]+cbv.z; o.w = acc[i][3]+cbv.w;
    *(float4*)&conv_raw[(rowbase + ty*4+i)*64 + tx*4] = o;
  }
}

// ---------------- K2M: merged msam attention + memory attention ----------------
__global__ __launch_bounds__(256) void k2m(const float* __restrict__ x,
    const float* __restrict__ conv_raw,
    const float* __restrict__ W1s, const float* __restrict__ Mv,
    const float* __restrict__ W1m, const float* __restrict__ W2m,
    float* __restrict__ memo) {
  __shared__ float xt[4][64*68];
  __shared__ float w1sT[640], w1mT[640], MvS[640], W2S[640];
  int tid = threadIdx.x;
  for (int i = tid; i < 640; i += 256) {
    int c = i / 10, m = i % 10;
    w1sT[m*64 + c] = W1s[i];
    w1mT[m*64 + c] = W1m[i];
    MvS[i] = Mv[i];
    W2S[i] = W2m[i];
  }
  int w = tid >> 6, lane = tid & 63;
  int R0 = blockIdx.x*256 + w*64;
  int n0 = R0 & (N_-1);
  int sb = R0 >> 11;
  int s  = sb % TT_;
  int b  = sb / TT_;
  const float* src = (s < T_) ? (x + (((size_t)b*T_ + s)*N_ + n0)*64)
                              : (conv_raw + (((size_t)b*TC_ + (s-T_))*N_ + n0)*64);
  float* xtw = xt[w];
  for (int it = 0; it < 16; ++it) {
    int flat = it*256 + lane*4;
    int r = flat >> 6, c = flat & 63;
    *(float4*)&xtw[r*68 + c] = *(const float4*)&src[(size_t)r*64 + c];
  }
  __syncthreads();
  if (s >= T_) {
    float p[10] = {};
    #pragma unroll
    for (int c4 = 0; c4 < 16; ++c4) {
      float4 v = *(float4*)&xtw[lane*68 + c4*4];
      #pragma unroll
      for (int j = 0; j < 10; ++j) {
        float4 wv = *(float4*)&w1sT[j*64 + c4*4];
        p[j] += v.x*wv.x + v.y*wv.y + v.z*wv.z + v.w*wv.w;
      }
    }
    float m = p[0];
    #pragma unroll
    for (int j = 1; j < 10; ++j) m = fmaxf(m, p[j]);
    float att[10]; float ssum = 0.f;
    #pragma unroll
    for (int j = 0; j < 10; ++j) { att[j] = __expf(p[j]-m); ssum += att[j]; }
    float inv = 1.f/ssum;
    #pragma unroll
    for (int j = 0; j < 10; ++j) att[j] *= inv;
    float mvr[10];
    #pragma unroll
    for (int j = 0; j < 10; ++j) mvr[j] = MvS[j*64 + lane];
    for (int r = 0; r < 64; ++r) {
      float add = 0.f;
      #pragma unroll
      for (int j = 0; j < 10; ++j) add += __shfl(att[j], r, 64) * mvr[j];
      xtw[r*68 + lane] += add;
    }
  }
  __syncthreads();
  float p[10] = {};
  #pragma unroll
  for (int c4 = 0; c4 < 16; ++c4) {
    float4 v = *(float4*)&xtw[lane*68 + c4*4];
    #pragma unroll
    for (int j = 0; j < 10; ++j) {
      float4 wv = *(float4*)&w1mT[j*64 + c4*4];
      p[j] += v.x*wv.x + v.y*wv.y + v.z*wv.z + v.w*wv.w;
    }
  }
  float m = p[0];
  #pragma unroll
  for (int j = 1; j < 10; ++j) m = fmaxf(m, p[j]);
  float att[10]; float ssum = 0.f;
  #pragma unroll
  for (int j = 0; j < 10; ++j) { att[j] = __expf(p[j]-m); ssum += att[j]; }
  float inv = 1.f/ssum;
  #pragma unroll
  for (int j = 0; j < 10; ++j) att[j] *= inv;
  float w2r[10];
  #pragma unroll
  for (int j = 0; j < 10; ++j) w2r[j] = W2S[j*64 + lane];
  float* dst = memo + (((size_t)b*TT_ + s)*N_ + n0)*64;
  for (int r = 0; r < 64; ++r) {
    float o = 0.f;
    #pragma unroll
    for (int j = 0; j < 10; ++j) o += __shfl(att[j], r, 64) * w2r[j];
    dst[(size_t)r*64 + lane] = o;
  }
}

// ---------------- K3M: time-mix einsum + residual, writes u only ----------------
__global__ __launch_bounds__(256) void k3_mix(const float* __restrict__ x,
    const float* __restrict__ memo, const float* __restrict__ Wt,
    float* __restrict__ u) {
  __shared__ float wt[T_*TT_];
  int tid = threadIdx.x;
  for (int i = tid; i < T_*TT_; i += 256) wt[i] = Wt[i];
  __syncthreads();
  int wv = blockIdx.x*4 + (tid >> 6);   // (b,n)
  int lane = tid & 63;
  int b = wv >> 11; int n = wv & (N_-1);
  float ms[TT_];
  #pragma unroll
  for (int s = 0; s < TT_; ++s)
    ms[s] = memo[(((size_t)b*TT_+s)*N_+n)*64 + lane];
  for (int t = 0; t < T_; ++t) {
    float acc = x[(((size_t)b*T_+t)*N_+n)*64 + lane];
    #pragma unroll
    for (int s = 0; s < TT_; ++s) acc += wt[t*TT_+s] * ms[s];
    u[((size_t)b*L_ + (size_t)t*N_ + n)*64 + lane] = acc;
  }
}

// ---------------- F1: LN + in_proj GEMM + conv1d + silu + x_proj + dt + scan agg ----------------
__global__ __launch_bounds__(256) void f1_chunk(const float* __restrict__ uIn,
    const float* __restrict__ ln_w, const float* __restrict__ ln_b,
    const float* __restrict__ W, const float* __restrict__ cw, const float* __restrict__ cb,
    const float* __restrict__ xpw, const float* __restrict__ dtw, const float* __restrict__ dtb,
    const float* __restrict__ A_log,
    float* __restrict__ xm, float* __restrict__ z,
    float* __restrict__ dt, float* __restrict__ Bm, float* __restrict__ Cm,
    float* __restrict__ aggP, float* __restrict__ aggS) {
  __shared__ float buf1[67*68];     // 18.2 KB: u rows row-major -> later xpT+pjs
  __shared__ float buf2[64*132];    // 33.8 KB: xv
  int tid = threadIdx.x;
  int cid = blockIdx.x;
  int b = cid / NCH_;
  int l0 = (cid % NCH_) * 64;
  size_t rbase = (size_t)b*L_ + l0;
  const float* ub = uIn + (size_t)b*L_*64;
  // phase 0: load u rows (67 incl. 3-row halo, zeros before seq start)
  for (int i = tid; i < 67*16; i += 256) {
    int rr = i >> 4, k4 = i & 15;
    int gl = l0 - 3 + rr;
    float4 v = make_float4(0.f,0.f,0.f,0.f);
    if (gl >= 0) v = *(const float4*)&ub[(size_t)gl*64 + k4*4];
    *(float4*)&buf1[rr*68 + k4*4] = v;
  }
  __syncthreads();
  // LN each valid row in place
  {
    int w = tid >> 6, lane = tid & 63;
    float lw = ln_w[lane], lb = ln_b[lane];
    for (int j = 0; j < 17; ++j) {
      int rr = j*4 + w;
      if (rr < 67 && (l0 - 3 + rr) >= 0) {
        float v = buf1[rr*68 + lane];
        float s1 = v, s2 = v*v;
        #pragma unroll
        for (int mm = 1; mm < 64; mm <<= 1) { s1 += __shfl_xor(s1, mm, 64); s2 += __shfl_xor(s2, mm, 64); }
        float mu = s1 * (1.f/64.f);
        float var = s2 * (1.f/64.f) - mu*mu;
        float iv = rsqrtf(var + 1e-5f);
        buf1[rr*68 + lane] = (v - mu) * iv * lw + lb;
      }
    }
  }
  __syncthreads();
  int c4 = tid & 31, rgrp = tid >> 5;
  // phase 1: merged xm-GEMM (11-row strip w/ halo) + z-GEMM, W from global (L2)
  float acc[11][4] = {};
  float acc2[8][4] = {};
  #pragma unroll 2
  for (int k = 0; k < 64; ++k) {
    float4 wx = *(const float4*)&W[(size_t)k*256 + c4*4];
    float4 wz = *(const float4*)&W[(size_t)k*256 + 128 + c4*4];
    float av[11];
    #pragma unroll
    for (int j = 0; j < 11; ++j) av[j] = buf1[(rgrp*8 + j)*68 + k];
    #pragma unroll
    for (int j = 0; j < 11; ++j) {
      acc[j][0] += av[j]*wx.x; acc[j][1] += av[j]*wx.y; acc[j][2] += av[j]*wx.z; acc[j][3] += av[j]*wx.w;
    }
    #pragma unroll
    for (int j = 0; j < 8; ++j) {
      float a = av[j+3];
      acc2[j][0] += a*wz.x; acc2[j][1] += a*wz.y; acc2[j][2] += a*wz.z; acc2[j][3] += a*wz.w;
    }
  }
  #pragma unroll
  for (int j = 0; j < 8; ++j) {
    float4 o; o.x=acc2[j][0]; o.y=acc2[j][1]; o.z=acc2[j][2]; o.w=acc2[j][3];
    *(float4*)&z[(rbase + rgrp*8 + j)*DI_ + c4*4] = o;
  }
  // conv + silu in registers
  float4 w0 = *(const float4*)&cw[0*DI_ + c4*4];
  float4 w1 = *(const float4*)&cw[1*DI_ + c4*4];
  float4 w2 = *(const float4*)&cw[2*DI_ + c4*4];
  float4 w3 = *(const float4*)&cw[3*DI_ + c4*4];
  float4 cbv = *(const float4*)&cb[c4*4];
  float sil[8][4];
  #pragma unroll
  for (int j = 0; j < 8; ++j) {
    float a0 = cbv.x + acc[j][0]*w0.x + acc[j+1][0]*w1.x + acc[j+2][0]*w2.x + acc[j+3][0]*w3.x;
    float a1 = cbv.y + acc[j][1]*w0.y + acc[j+1][1]*w1.y + acc[j+2][1]*w2.y + acc[j+3][1]*w3.y;
    float a2 = cbv.z + acc[j][2]*w0.z + acc[j+1][2]*w1.z + acc[j+2][2]*w2.z + acc[j+3][2]*w3.z;
    float a3 = cbv.w + acc[j][3]*w0.w + acc[j+1][3]*w1.w + acc[j+2][3]*w2.w + acc[j+3][3]*w3.w;
    sil[j][0] = a0 / (1.f + __expf(-a0));
    sil[j][1] = a1 / (1.f + __expf(-a1));
    sil[j][2] = a2 / (1.f + __expf(-a2));
    sil[j][3] = a3 / (1.f + __expf(-a3));
  }
  // phase 2: xv into buf2, xm to global; then xpT over buf1
  float* xv = buf2;
  #pragma unroll
  for (int j = 0; j < 8; ++j) {
    float4 o; o.x=sil[j][0]; o.y=sil[j][1]; o.z=sil[j][2]; o.w=sil[j][3];
    *(float4*)&xv[(rgrp*8+j)*132 + c4*4] = o;
    *(float4*)&xm[(rbase + rgrp*8 + j)*DI_ + c4*4] = o;
  }
  __syncthreads();
  float* xpT = buf1;                  // [20][132]
  float* pjs = buf1 + 2688;           // [64][24]
  for (int i = tid; i < 2560; i += 256) {
    int c = i / 20, j = i % 20;
    xpT[j*132 + c] = xpw[i];
  }
  __syncthreads();
  // phase 3: x_proj mini-GEMM
  {
    int row = tid >> 2, q = tid & 3, j0 = q*5;
    float a5[5] = {0,0,0,0,0};
    for (int k4 = 0; k4 < 32; ++k4) {
      float4 a4 = *(float4*)&xv[row*132 + k4*4];
      #pragma unroll
      for (int jj = 0; jj < 5; ++jj) {
        float4 b4 = *(float4*)&xpT[(j0+jj)*132 + k4*4];
        a5[jj] += a4.x*b4.x + a4.y*b4.y + a4.z*b4.z + a4.w*b4.w;
      }
    }
    #pragma unroll
    for (int jj = 0; jj < 5; ++jj) pjs[row*24 + j0+jj] = a5[jj];
  }
  __syncthreads();
  // phase 4: dt epilogue + B/C store
  {
    float4 dw0 = *(const float4*)&dtw[0*DI_ + c4*4];
    float4 dw1 = *(const float4*)&dtw[1*DI_ + c4*4];
    float4 dw2 = *(const float4*)&dtw[2*DI_ + c4*4];
    float4 dw3 = *(const float4*)&dtw[3*DI_ + c4*4];
    float4 dbv = *(const float4*)&dtb[c4*4];
    #pragma unroll
    for (int j = 0; j < 8; ++j) {
      int row = rgrp*8 + j;
      float p0 = pjs[row*24+0], p1 = pjs[row*24+1], p2 = pjs[row*24+2], p3 = pjs[row*24+3];
      float a0 = dbv.x + p0*dw0.x + p1*dw1.x + p2*dw2.x + p3*dw3.x;
      float a1 = dbv.y + p0*dw0.y + p1*dw1.y + p2*dw2.y + p3*dw3.y;
      float a2 = dbv.z + p0*dw0.z + p1*dw1.z + p2*dw2.z + p3*dw3.z;
      float a3 = dbv.w + p0*dw0.w + p1*dw1.w + p2*dw2.w + p3*dw3.w;
      float4 o;
      o.x = (a0 > 15.f) ? a0 : __logf(1.f + __expf(a0));
      o.y = (a1 > 15.f) ? a1 : __logf(1.f + __expf(a1));
      o.z = (a2 > 15.f) ? a2 : __logf(1.f + __expf(a2));
      o.w = (a3 > 15.f) ? a3 : __logf(1.f + __expf(a3));
      *(float4*)&dt[(rbase + row)*DI_ + c4*4] = o;
    }
    int row = tid >> 2, q = tid & 3;
    float4 o;
    o.x = pjs[row*24 + 4 + q*4 + 0];
    o.y = pjs[row*24 + 4 + q*4 + 1];
    o.z = pjs[row*24 + 4 + q*4 + 2];
    o.w = pjs[row*24 + 4 + q*4 + 3];
    if (q < 2) *(float4*)&Bm[(rbase+row)*8 + q*4] = o;
    else       *(float4*)&Cm[(rbase+row)*8 + (q-2)*4] = o;
  }
  // phase 5: chunk-local scan aggregates
  {
    int d = tid & 127, q = tid >> 7;
    float4 av4 = *(const float4*)&A_log[d*8 + q*4];
    float a0 = -__expf(av4.x), a1 = -__expf(av4.y), a2 = -__expf(av4.z), a3 = -__expf(av4.w);
    float dtw0 = dtw[0*DI_+d], dtw1 = dtw[1*DI_+d], dtw2 = dtw[2*DI_+d], dtw3 = dtw[3*DI_+d];
    float dtbd = dtb[d];
    float P0=1.f,P1=1.f,P2=1.f,P3=1.f, S0=0.f,S1=0.f,S2=0.f,S3=0.f;
    for (int r = 0; r < 64; ++r) {
      float p0 = pjs[r*24+0], p1 = pjs[r*24+1], p2 = pjs[r*24+2], p3 = pjs[r*24+3];
      float aa = dtbd + p0*dtw0 + p1*dtw1 + p2*dtw2 + p3*dtw3;
      float dtv = (aa > 15.f) ? aa : __logf(1.f + __expf(aa));
      float dx = dtv * xv[r*132 + d];
      float b0 = pjs[r*24 + 4 + q*4 + 0];
      float b1 = pjs[r*24 + 4 + q*4 + 1];
      float b2 = pjs[r*24 + 4 + q*4 + 2];
      float b3 = pjs[r*24 + 4 + q*4 + 3];
      float e0 = __expf(dtv*a0), e1 = __expf(dtv*a1), e2 = __expf(dtv*a2), e3 = __expf(dtv*a3);
      P0*=e0; P1*=e1; P2*=e2; P3*=e3;
      S0 = e0*S0 + dx*b0; S1 = e1*S1 + dx*b1; S2 = e2*S2 + dx*b2; S3 = e3*S3 + dx*b3;
    }
    size_t o = (((size_t)cid)*128 + d)*8 + q*4;
    float4 pv; pv.x=P0; pv.y=P1; pv.z=P2; pv.w=P3;
    float4 sv; sv.x=S0; sv.y=S1; sv.z=S2; sv.w=S3;
    *(float4*)&aggP[o] = pv;
    *(float4*)&aggS[o] = sv;
  }
}

// ---------------- S2: serial combine across chunks ----------------
__global__ __launch_bounds__(256) void s2_scan_chunks(const float* __restrict__ aggP,
    const float* __restrict__ aggS, float* __restrict__ hIn) {
  int gidx = blockIdx.x*256 + threadIdx.x;   // (b, d*8+s)
  int b = gidx >> 10; int rem = gidx & 1023;
  float S = 0.f;
  #pragma unroll 8
  for (int ch = 0; ch < NCH_; ++ch) {
    size_t o = ((size_t)b*NCH_ + ch)*1024 + rem;
    hIn[o] = S;
    S = aggP[o]*S + aggS[o];
  }
}

// ---------------- F3: pair-scan apply + gate + out_proj GEMM + residual ----------------
__global__ __launch_bounds__(256) void f3_scan_out(const float* __restrict__ dt,
    const float* __restrict__ xm, const float* __restrict__ z,
    const float* __restrict__ Bm, const float* __restrict__ Cm,
    const float* __restrict__ hIn, const float* __restrict__ A_log,
    const float* __restrict__ Dp, const float* __restrict__ Wo,
    const float* __restrict__ u, float* __restrict__ out) {
  __shared__ float y2t[64*132];   // 33.8 KB
  __shared__ float bc[64*16];     // 4 KB
  int tid = threadIdx.x;
  int cid = blockIdx.x;
  int b = cid / NCH_;
  int l0 = (cid % NCH_) * 64;
  size_t rbase = (size_t)b*L_ + l0;
  {
    int row = tid >> 2, q = tid & 3;
    float4 v = (q < 2) ? *(const float4*)&Bm[(rbase+row)*8 + q*4]
                       : *(const float4*)&Cm[(rbase+row)*8 + (q-2)*4];
    *(float4*)&bc[row*16 + q*4] = v;
  }
  __syncthreads();
  // pair-scan: thread = (d, q); adjacent lanes combine via shfl_xor(1)
  {
    int d = tid >> 1, q = tid & 1;
    float4 av = *(const float4*)&A_log[d*8 + q*4];
    float a0 = -__expf(av.x), a1 = -__expf(av.y), a2 = -__expf(av.z), a3 = -__expf(av.w);
    float4 hv = *(const float4*)&hIn[(((size_t)cid)*128 + d)*8 + q*4];
    float h0 = hv.x, h1 = hv.y, h2 = hv.z, h3 = hv.w;
    float Dpd = Dp[d];
    #pragma unroll 4
    for (int r = 0; r < 64; ++r) {
      size_t rr = rbase + r;
      float dtv = dt[rr*DI_ + d];
      float xmv = xm[rr*DI_ + d];
      float zv  = z[rr*DI_ + d];
      float dx = dtv * xmv;
      float part = q ? 0.f : xmv * Dpd;
      float e0 = __expf(dtv*a0), e1 = __expf(dtv*a1), e2 = __expf(dtv*a2), e3 = __expf(dtv*a3);
      h0 = e0*h0 + dx*bc[r*16 + q*4 + 0];
      h1 = e1*h1 + dx*bc[r*16 + q*4 + 1];
      h2 = e2*h2 + dx*bc[r*16 + q*4 + 2];
      h3 = e3*h3 + dx*bc[r*16 + q*4 + 3];
      part += h0*bc[r*16 + 8 + q*4 + 0];
      part += h1*bc[r*16 + 8 + q*4 + 1];
      part += h2*bc[r*16 + 8 + q*4 + 2];
      part += h3*bc[r*16 + 8 + q*4 + 3];
      part += __shfl_xor(part, 1, 64);
      if (q == 0) {
        float sg = 1.f / (1.f + __expf(-zv));
        y2t[r*132 + d] = part * zv * sg;
      }
    }
  }
  __syncthreads();
  // out[64x64] = y2t[64x128] @ Wo[128x64] + u
  int tx = tid & 15, ty = tid >> 4;
  int col = tx*4;
  float acc[4][4] = {};
  #pragma unroll 2
  for (int k = 0; k < 128; ++k) {
    float4 bv = *(const float4*)&Wo[(size_t)k*64 + col];
    #pragma unroll
    for (int i = 0; i < 4; ++i) {
      float a = y2t[(ty*4+i)*132 + k];
      acc[i][0] += a*bv.x; acc[i][1] += a*bv.y; acc[i][2] += a*bv.z; acc[i][3] += a*bv.w;
    }
  }
  #pragma unroll
  for (int i = 0; i < 4; ++i) {
    size_t row = rbase + ty*4 + i;
    float4 uv = *(const float4*)&u[row*64 + col];
    float4 o;
    o.x = uv.x + acc[i][0]; o.y = uv.y + acc[i][1]; o.z = uv.z + acc[i][2]; o.w = uv.w + acc[i][3];
    *(float4*)&out[row*64 + col] = o;
  }
}

// ---------------- launch ----------------
extern "C" void kernel_launch(void* const* d_in, const int* in_sizes, int n_in,
                              void* d_out, int out_size, void* d_ws, size_t ws_size,
                              hipStream_t stream) {
  const float* x        = (const float*)d_in[0];
  const float* mconv_w  = (const float*)d_in[1];
  const float* mconv_b  = (const float*)d_in[2];
  const float* mWq      = (const float*)d_in[3];
  const float* mMk      = (const float*)d_in[4];
  const float* mMv      = (const float*)d_in[5];
  const float* memWq    = (const float*)d_in[6];
  const float* memM     = (const float*)d_in[7];
  const float* memWo    = (const float*)d_in[8];
  const float* memWt    = (const float*)d_in[9];
  const float* ln_w     = (const float*)d_in[10];
  const float* ln_b     = (const float*)d_in[11];
  const float* in_proj  = (const float*)d_in[12];
  const float* conv1d_w = (const float*)d_in[13];
  const float* conv1d_b = (const float*)d_in[14];
  const float* x_proj   = (const float*)d_in[15];
  const float* dt_w     = (const float*)d_in[16];
  const float* dt_b     = (const float*)d_in[17];
  const float* A_log    = (const float*)d_in[18];
  const float* Dp       = (const float*)d_in[19];
  const float* out_proj = (const float*)d_in[20];
  float* out = (float*)d_out;
  float* ws  = (float*)d_ws;

  float* W1      = ws + 0;          // 640
  float* W1m     = ws + 640;        // 640
  float* W2m     = ws + 1280;       // 640
  float* conv_raw= ws + 2048;       // 1,310,720
  float* memo    = ws + 1312768;    // 4,456,448
  float* u       = ws + 5769216;    // 3,145,728
  float* z       = ws + 8914944;    // 6,291,456
  float* xm      = ws + 15206400;   // 6,291,456
  float* dt      = ws + 21497856;   // 6,291,456
  float* Bm      = ws + 27789312;   // 393,216
  float* Cm      = ws + 28182528;   // 393,216
  float* aggP    = ws + 28575744;   // 786,432
  float* aggS    = ws + 29362176;   // 786,432
  float* hIn     = ws + 30148608;   // 786,432

  hipLaunchKernelGGL(k0_precomp, dim3(1), dim3(64), 0, stream,
                     mWq, mMk, memWq, memM, memWo, W1, W1m, W2m);
  hipLaunchKernelGGL(k1a_conv, dim3(32, 5, 2), dim3(256), 0, stream,
                     x, mconv_w, mconv_b, conv_raw);
  hipLaunchKernelGGL(k2m, dim3(272), dim3(256), 0, stream,
                     x, conv_raw, W1, mMv, W1m, W2m, memo);
  hipLaunchKernelGGL(k3_mix, dim3(1024), dim3(256), 0, stream,
                     x, memo, memWt, u);
  hipLaunchKernelGGL(f1_chunk, dim3(768), dim3(256), 0, stream,
                     u, ln_w, ln_b, in_proj, conv1d_w, conv1d_b,
                     x_proj, dt_w, dt_b, A_log,
                     xm, z, dt, Bm, Cm, aggP, aggS);
  hipLaunchKernelGGL(s2_scan_chunks, dim3(8), dim3(256), 0, stream,
                     aggP, aggS, hIn);
  hipLaunchKernelGGL(f3_scan_out, dim3(768), dim3(256), 0, stream,
                     dt, xm, z, Bm, Cm, hIn, A_log, Dp, out_proj, u, out);
}

// Round 8
// 237.524 us; speedup vs baseline: 1.0749x; 1.0749x over previous
//
#include <hip/hip_runtime.h>
#include <math.h>

#define B_  2
#define T_  12
#define N_  2048
#define D_  64
#define DI_ 128
#define DS_ 8
#define NM_ 10
#define CK_ 3
#define CS_ 2
#define TC_ 5
#define TT_ 17
#define L_  (T_*N_)        // 24576
#define CHUNK_ 64
#define NCH_ (L_/CHUNK_)   // 384

// ---------------- K0: fold small weight products ----------------
__global__ void k0_precomp(const float* __restrict__ msam_Wq, const float* __restrict__ msam_Mk,
                           const float* __restrict__ mem_Wq, const float* __restrict__ mem_M,
                           const float* __restrict__ mem_Wo,
                           float* __restrict__ W1, float* __restrict__ W1m, float* __restrict__ W2m) {
  int d = threadIdx.x;
  if (d >= 64) return;
  for (int m = 0; m < NM_; ++m) {
    float a = 0.f;
    for (int j = 0; j < 4; ++j) a += msam_Wq[d*4+j] * msam_Mk[m*4+j];
    W1[d*10+m] = a;
    float b = 0.f;
    for (int k = 0; k < 64; ++k) b += mem_Wq[d*64+k] * mem_M[m*64+k];
    W1m[d*10+m] = b;
    float c = 0.f;
    for (int k = 0; k < 64; ++k) c += mem_M[m*64+k] * mem_Wo[k*64+d];
    W2m[m*64+d] = c;
  }
}

// ---------------- K1a: msam conv as tiled fp32 GEMM ----------------
__global__ __launch_bounds__(256) void k1a_conv(const float* __restrict__ x,
    const float* __restrict__ cw, const float* __restrict__ cb,
    float* __restrict__ conv_raw) {
  __shared__ float ats[64*65];
  __shared__ float bts[192*64];
  int tid = threadIdx.x;
  int n0 = blockIdx.x * 64;
  int tc = blockIdx.y;
  int b  = blockIdx.z;
  for (int i = tid; i < 3072; i += 256)
    ((float4*)bts)[i] = ((const float4*)cw)[i];
  int ty = tid >> 4, tx = tid & 15;
  float acc[4][4] = {};
  for (int kk = 0; kk < 3; ++kk) {
    __syncthreads();
    const float* xs = x + (((size_t)b*T_ + (2*tc+kk))*N_ + n0)*64;
    for (int i = tid; i < 1024; i += 256) {
      int r = i >> 4, c = (i & 15) * 4;
      float4 v = ((const float4*)xs)[i];
      ats[r*65+c+0]=v.x; ats[r*65+c+1]=v.y; ats[r*65+c+2]=v.z; ats[r*65+c+3]=v.w;
    }
    __syncthreads();
    for (int k = 0; k < 64; ++k) {
      float a0 = ats[(ty*4+0)*65 + k];
      float a1 = ats[(ty*4+1)*65 + k];
      float a2 = ats[(ty*4+2)*65 + k];
      float a3 = ats[(ty*4+3)*65 + k];
      float4 bv = *(float4*)&bts[(kk*64+k)*64 + tx*4];
      acc[0][0]+=a0*bv.x; acc[0][1]+=a0*bv.y; acc[0][2]+=a0*bv.z; acc[0][3]+=a0*bv.w;
      acc[1][0]+=a1*bv.x; acc[1][1]+=a1*bv.y; acc[1][2]+=a1*bv.z; acc[1][3]+=a1*bv.w;
      acc[2][0]+=a2*bv.x; acc[2][1]+=a2*bv.y; acc[2][2]+=a2*bv.z; acc[2][3]+=a2*bv.w;
      acc[3][0]+=a3*bv.x; acc[3][1]+=a3*bv.y; acc[3][2]+=a3*bv.z; acc[3][3]+=a3*bv.w;
    }
  }
  float4 cbv = *(const float4*)&cb[tx*4];
  size_t rowbase = ((size_t)b*TC_ + tc)*N_ + n0;
  #pragma unroll
  for (int i = 0; i < 4; ++i) {
    float4 o;
    o.x = acc[i][0]+cbv.x; o.y = acc[i][1]+cbv.y; o.z = acc[i][2]+cbv.z; o.w = acc[i][3]+cbv.w;
    *(float4*)&conv_raw[(rowbase + ty*4+i)*64 + tx*4] = o;
  }
}

// ---------------- K2M: msam + mem attention, 4 threads/row, 1088 blocks ----------------
__global__ __launch_bounds__(256) void k2m(const float* __restrict__ x,
    const float* __restrict__ conv_raw,
    const float* __restrict__ W1s, const float* __restrict__ Mv,
    const float* __restrict__ W1m, const float* __restrict__ W2m,
    float* __restrict__ memo) {
  __shared__ float xt[64*68];
  __shared__ float w1sT[640], w1mT[640], MvS[640], W2S[640];
  int tid = threadIdx.x;
  for (int i = tid; i < 640; i += 256) {
    int c = i / 10, m = i % 10;
    w1sT[m*64 + c] = W1s[i];
    w1mT[m*64 + c] = W1m[i];
    MvS[i] = Mv[i];
    W2S[i] = W2m[i];
  }
  int tile = blockIdx.x;          // 0..1087
  int n0 = (tile & 31) * 64;
  int sb = tile >> 5;             // b*TT + s
  int s  = sb % TT_;
  int b  = sb / TT_;
  const float* src = (s < T_) ? (x + (((size_t)b*T_ + s)*N_ + n0)*64)
                              : (conv_raw + (((size_t)b*TC_ + (s-T_))*N_ + n0)*64);
  for (int i = tid; i < 1024; i += 256) {
    int r = i >> 4, c4 = i & 15;
    *(float4*)&xt[r*68 + c4*4] = *(const float4*)&src[(size_t)r*64 + c4*4];
  }
  __syncthreads();
  int r = tid >> 2, g = tid & 3;     // 4 threads per row; k/c range g*16..g*16+15
  if (s >= T_) {
    float p[10] = {};
    #pragma unroll
    for (int k4 = 0; k4 < 4; ++k4) {
      float4 v = *(float4*)&xt[r*68 + g*16 + k4*4];
      #pragma unroll
      for (int j = 0; j < 10; ++j) {
        float4 wv = *(float4*)&w1sT[j*64 + g*16 + k4*4];
        p[j] += v.x*wv.x + v.y*wv.y + v.z*wv.z + v.w*wv.w;
      }
    }
    #pragma unroll
    for (int j = 0; j < 10; ++j) {
      p[j] += __shfl_xor(p[j], 1, 64);
      p[j] += __shfl_xor(p[j], 2, 64);
    }
    float m = p[0];
    #pragma unroll
    for (int j = 1; j < 10; ++j) m = fmaxf(m, p[j]);
    float att[10]; float ssum = 0.f;
    #pragma unroll
    for (int j = 0; j < 10; ++j) { att[j] = __expf(p[j]-m); ssum += att[j]; }
    float inv = 1.f/ssum;
    float4 xr[4];
    #pragma unroll
    for (int c4 = 0; c4 < 4; ++c4) xr[c4] = *(float4*)&xt[r*68 + g*16 + c4*4];
    #pragma unroll
    for (int j = 0; j < 10; ++j) {
      float aj = att[j]*inv;
      #pragma unroll
      for (int c4 = 0; c4 < 4; ++c4) {
        float4 mv = *(float4*)&MvS[j*64 + g*16 + c4*4];
        xr[c4].x += aj*mv.x; xr[c4].y += aj*mv.y; xr[c4].z += aj*mv.z; xr[c4].w += aj*mv.w;
      }
    }
    #pragma unroll
    for (int c4 = 0; c4 < 4; ++c4) *(float4*)&xt[r*68 + g*16 + c4*4] = xr[c4];
    __syncthreads();
  }
  // mem attention
  float p[10] = {};
  #pragma unroll
  for (int k4 = 0; k4 < 4; ++k4) {
    float4 v = *(float4*)&xt[r*68 + g*16 + k4*4];
    #pragma unroll
    for (int j = 0; j < 10; ++j) {
      float4 wv = *(float4*)&w1mT[j*64 + g*16 + k4*4];
      p[j] += v.x*wv.x + v.y*wv.y + v.z*wv.z + v.w*wv.w;
    }
  }
  #pragma unroll
  for (int j = 0; j < 10; ++j) {
    p[j] += __shfl_xor(p[j], 1, 64);
    p[j] += __shfl_xor(p[j], 2, 64);
  }
  float m = p[0];
  #pragma unroll
  for (int j = 1; j < 10; ++j) m = fmaxf(m, p[j]);
  float att[10]; float ssum = 0.f;
  #pragma unroll
  for (int j = 0; j < 10; ++j) { att[j] = __expf(p[j]-m); ssum += att[j]; }
  float inv = 1.f/ssum;
  float4 o4[4] = {};
  #pragma unroll
  for (int j = 0; j < 10; ++j) {
    float aj = att[j]*inv;
    #pragma unroll
    for (int c4 = 0; c4 < 4; ++c4) {
      float4 wv = *(float4*)&W2S[j*64 + g*16 + c4*4];
      o4[c4].x += aj*wv.x; o4[c4].y += aj*wv.y; o4[c4].z += aj*wv.z; o4[c4].w += aj*wv.w;
    }
  }
  float* dst = memo + (((size_t)b*TT_ + s)*N_ + n0 + r)*64;
  #pragma unroll
  for (int c4 = 0; c4 < 4; ++c4) *(float4*)&dst[g*16 + c4*4] = o4[c4];
}

// ---------------- K3M: time-mix einsum + residual, writes u only ----------------
__global__ __launch_bounds__(256) void k3_mix(const float* __restrict__ x,
    const float* __restrict__ memo, const float* __restrict__ Wt,
    float* __restrict__ u) {
  __shared__ float wt[T_*TT_];
  int tid = threadIdx.x;
  for (int i = tid; i < T_*TT_; i += 256) wt[i] = Wt[i];
  __syncthreads();
  int wv = blockIdx.x*4 + (tid >> 6);   // (b,n)
  int lane = tid & 63;
  int b = wv >> 11; int n = wv & (N_-1);
  float ms[TT_];
  #pragma unroll
  for (int s = 0; s < TT_; ++s)
    ms[s] = memo[(((size_t)b*TT_+s)*N_+n)*64 + lane];
  for (int t = 0; t < T_; ++t) {
    float acc = x[(((size_t)b*T_+t)*N_+n)*64 + lane];
    #pragma unroll
    for (int s = 0; s < TT_; ++s) acc += wt[t*TT_+s] * ms[s];
    u[((size_t)b*L_ + (size_t)t*N_ + n)*64 + lane] = acc;
  }
}

// ---------------- F1 (512 thr): LN + in_proj GEMM + conv1d + silu + x_proj + dt + scan agg ----------------
__global__ __launch_bounds__(512) void f1_chunk(const float* __restrict__ uIn,
    const float* __restrict__ ln_w, const float* __restrict__ ln_b,
    const float* __restrict__ W, const float* __restrict__ cw, const float* __restrict__ cb,
    const float* __restrict__ xpw, const float* __restrict__ dtw, const float* __restrict__ dtb,
    const float* __restrict__ A_log,
    float* __restrict__ xm, float* __restrict__ z,
    float* __restrict__ dt, float* __restrict__ Bm, float* __restrict__ Cm,
    float* __restrict__ aggP, float* __restrict__ aggS) {
  __shared__ float buf1[67*68];     // u rows row-major -> later xpT+pjs
  __shared__ float buf2[64*132];    // xv
  int tid = threadIdx.x;            // 0..511
  int cid = blockIdx.x;
  int b = cid / NCH_;
  int l0 = (cid % NCH_) * 64;
  size_t rbase = (size_t)b*L_ + l0;
  const float* ub = uIn + (size_t)b*L_*64;
  // phase 0: load u rows (67 incl. halo)
  for (int i = tid; i < 67*16; i += 512) {
    int rr = i >> 4, k4 = i & 15;
    int gl = l0 - 3 + rr;
    float4 v = make_float4(0.f,0.f,0.f,0.f);
    if (gl >= 0) v = *(const float4*)&ub[(size_t)gl*64 + k4*4];
    *(float4*)&buf1[rr*68 + k4*4] = v;
  }
  __syncthreads();
  // LN in place (8 warps)
  {
    int w = tid >> 6, lane = tid & 63;
    float lw = ln_w[lane], lb = ln_b[lane];
    for (int j = 0; j < 9; ++j) {
      int rr = j*8 + w;
      if (rr < 67 && (l0 - 3 + rr) >= 0) {
        float v = buf1[rr*68 + lane];
        float s1 = v, s2 = v*v;
        #pragma unroll
        for (int mm = 1; mm < 64; mm <<= 1) { s1 += __shfl_xor(s1, mm, 64); s2 += __shfl_xor(s2, mm, 64); }
        float mu = s1 * (1.f/64.f);
        float var = s2 * (1.f/64.f) - mu*mu;
        float iv = rsqrtf(var + 1e-5f);
        buf1[rr*68 + lane] = (v - mu) * iv * lw + lb;
      }
    }
  }
  __syncthreads();
  int cp = tid & 63;          // col pair: cols cp*2, cp*2+1
  int rgrp = tid >> 6;        // 0..7 -> rows rgrp*8..+7 (+3 halo)
  // phase 1: xm-GEMM (11-row strip) + z-GEMM, W from L2
  float acc[11][2] = {};
  float acc2[8][2] = {};
  #pragma unroll 2
  for (int k = 0; k < 64; ++k) {
    float2 wx = *(const float2*)&W[(size_t)k*256 + cp*2];
    float2 wz = *(const float2*)&W[(size_t)k*256 + 128 + cp*2];
    float av[11];
    #pragma unroll
    for (int j = 0; j < 11; ++j) av[j] = buf1[(rgrp*8 + j)*68 + k];
    #pragma unroll
    for (int j = 0; j < 11; ++j) {
      acc[j][0] += av[j]*wx.x; acc[j][1] += av[j]*wx.y;
    }
    #pragma unroll
    for (int j = 0; j < 8; ++j) {
      acc2[j][0] += av[j+3]*wz.x; acc2[j][1] += av[j+3]*wz.y;
    }
  }
  #pragma unroll
  for (int j = 0; j < 8; ++j) {
    float2 o; o.x = acc2[j][0]; o.y = acc2[j][1];
    *(float2*)&z[(rbase + rgrp*8 + j)*DI_ + cp*2] = o;
  }
  // conv + silu in registers
  float2 w0 = *(const float2*)&cw[0*DI_ + cp*2];
  float2 w1 = *(const float2*)&cw[1*DI_ + cp*2];
  float2 w2 = *(const float2*)&cw[2*DI_ + cp*2];
  float2 w3 = *(const float2*)&cw[3*DI_ + cp*2];
  float2 cbv = *(const float2*)&cb[cp*2];
  float sil[8][2];
  #pragma unroll
  for (int j = 0; j < 8; ++j) {
    float a0 = cbv.x + acc[j][0]*w0.x + acc[j+1][0]*w1.x + acc[j+2][0]*w2.x + acc[j+3][0]*w3.x;
    float a1 = cbv.y + acc[j][1]*w0.y + acc[j+1][1]*w1.y + acc[j+2][1]*w2.y + acc[j+3][1]*w3.y;
    sil[j][0] = a0 / (1.f + __expf(-a0));
    sil[j][1] = a1 / (1.f + __expf(-a1));
  }
  // phase 2: xv into buf2 + xm to global
  #pragma unroll
  for (int j = 0; j < 8; ++j) {
    float2 o; o.x = sil[j][0]; o.y = sil[j][1];
    *(float2*)&buf2[(rgrp*8+j)*132 + cp*2] = o;
    *(float2*)&xm[(rbase + rgrp*8 + j)*DI_ + cp*2] = o;
  }
  __syncthreads();
  float* xpT = buf1;                  // [20][132]
  float* pjs = buf1 + 2688;           // [64][24]
  for (int i = tid; i < 2560; i += 512) {
    int c = i / 20, j = i % 20;
    xpT[j*132 + c] = xpw[i];
  }
  __syncthreads();
  // phase 3: x_proj mini-GEMM (first 256 threads)
  if (tid < 256) {
    int row = tid >> 2, q = tid & 3, j0 = q*5;
    float a5[5] = {0,0,0,0,0};
    for (int k4 = 0; k4 < 32; ++k4) {
      float4 a4 = *(float4*)&buf2[row*132 + k4*4];
      #pragma unroll
      for (int jj = 0; jj < 5; ++jj) {
        float4 b4 = *(float4*)&xpT[(j0+jj)*132 + k4*4];
        a5[jj] += a4.x*b4.x + a4.y*b4.y + a4.z*b4.z + a4.w*b4.w;
      }
    }
    #pragma unroll
    for (int jj = 0; jj < 5; ++jj) pjs[row*24 + j0+jj] = a5[jj];
  }
  __syncthreads();
  // phase 4: dt epilogue (all 512) + B/C store (first 256)
  {
    float2 dw0 = *(const float2*)&dtw[0*DI_ + cp*2];
    float2 dw1 = *(const float2*)&dtw[1*DI_ + cp*2];
    float2 dw2 = *(const float2*)&dtw[2*DI_ + cp*2];
    float2 dw3 = *(const float2*)&dtw[3*DI_ + cp*2];
    float2 dbv = *(const float2*)&dtb[cp*2];
    #pragma unroll
    for (int j = 0; j < 8; ++j) {
      int row = rgrp*8 + j;
      float p0 = pjs[row*24+0], p1 = pjs[row*24+1], p2 = pjs[row*24+2], p3 = pjs[row*24+3];
      float a0 = dbv.x + p0*dw0.x + p1*dw1.x + p2*dw2.x + p3*dw3.x;
      float a1 = dbv.y + p0*dw0.y + p1*dw1.y + p2*dw2.y + p3*dw3.y;
      float2 o;
      o.x = (a0 > 15.f) ? a0 : __logf(1.f + __expf(a0));
      o.y = (a1 > 15.f) ? a1 : __logf(1.f + __expf(a1));
      *(float2*)&dt[(rbase + row)*DI_ + cp*2] = o;
    }
    if (tid < 256) {
      int row = tid >> 2, q = tid & 3;
      float4 o;
      o.x = pjs[row*24 + 4 + q*4 + 0];
      o.y = pjs[row*24 + 4 + q*4 + 1];
      o.z = pjs[row*24 + 4 + q*4 + 2];
      o.w = pjs[row*24 + 4 + q*4 + 3];
      if (q < 2) *(float4*)&Bm[(rbase+row)*8 + q*4] = o;
      else       *(float4*)&Cm[(rbase+row)*8 + (q-2)*4] = o;
    }
  }
  // phase 5: chunk-local scan aggregates (first 256 threads)
  if (tid < 256) {
    int d = tid & 127, q = tid >> 7;
    float4 av4 = *(const float4*)&A_log[d*8 + q*4];
    float a0 = -__expf(av4.x), a1 = -__expf(av4.y), a2 = -__expf(av4.z), a3 = -__expf(av4.w);
    float dtw0 = dtw[0*DI_+d], dtw1 = dtw[1*DI_+d], dtw2 = dtw[2*DI_+d], dtw3 = dtw[3*DI_+d];
    float dtbd = dtb[d];
    float P0=1.f,P1=1.f,P2=1.f,P3=1.f, S0=0.f,S1=0.f,S2=0.f,S3=0.f;
    for (int r = 0; r < 64; ++r) {
      float p0 = pjs[r*24+0], p1 = pjs[r*24+1], p2 = pjs[r*24+2], p3 = pjs[r*24+3];
      float aa = dtbd + p0*dtw0 + p1*dtw1 + p2*dtw2 + p3*dtw3;
      float dtv = (aa > 15.f) ? aa : __logf(1.f + __expf(aa));
      float dx = dtv * buf2[r*132 + d];
      float b0 = pjs[r*24 + 4 + q*4 + 0];
      float b1 = pjs[r*24 + 4 + q*4 + 1];
      float b2 = pjs[r*24 + 4 + q*4 + 2];
      float b3 = pjs[r*24 + 4 + q*4 + 3];
      float e0 = __expf(dtv*a0), e1 = __expf(dtv*a1), e2 = __expf(dtv*a2), e3 = __expf(dtv*a3);
      P0*=e0; P1*=e1; P2*=e2; P3*=e3;
      S0 = e0*S0 + dx*b0; S1 = e1*S1 + dx*b1; S2 = e2*S2 + dx*b2; S3 = e3*S3 + dx*b3;
    }
    size_t o = (((size_t)cid)*128 + d)*8 + q*4;
    float4 pv; pv.x=P0; pv.y=P1; pv.z=P2; pv.w=P3;
    float4 sv; sv.x=S0; sv.y=S1; sv.z=S2; sv.w=S3;
    *(float4*)&aggP[o] = pv;
    *(float4*)&aggS[o] = sv;
  }
}

// ---------------- S2: serial combine across chunks ----------------
__global__ __launch_bounds__(256) void s2_scan_chunks(const float* __restrict__ aggP,
    const float* __restrict__ aggS, float* __restrict__ hIn) {
  int gidx = blockIdx.x*256 + threadIdx.x;   // (b, d*8+s)
  int b = gidx >> 10; int rem = gidx & 1023;
  float S = 0.f;
  #pragma unroll 8
  for (int ch = 0; ch < NCH_; ++ch) {
    size_t o = ((size_t)b*NCH_ + ch)*1024 + rem;
    hIn[o] = S;
    S = aggP[o]*S + aggS[o];
  }
}

// ---------------- F3 (512 thr): quad-scan apply + gate + out_proj GEMM + residual ----------------
__global__ __launch_bounds__(512) void f3_scan_out(const float* __restrict__ dt,
    const float* __restrict__ xm, const float* __restrict__ z,
    const float* __restrict__ Bm, const float* __restrict__ Cm,
    const float* __restrict__ hIn, const float* __restrict__ A_log,
    const float* __restrict__ Dp, const float* __restrict__ Wo,
    const float* __restrict__ u, float* __restrict__ out) {
  __shared__ float y2t[64*129];   // 33 KB, stride 129 = conflict-free GEMM reads
  __shared__ float bc[64*16];     // 4 KB
  int tid = threadIdx.x;          // 0..511
  int cid = blockIdx.x;
  int b = cid / NCH_;
  int l0 = (cid % NCH_) * 64;
  size_t rbase = (size_t)b*L_ + l0;
  if (tid < 256) {
    int row = tid >> 2, q = tid & 3;
    float4 v = (q < 2) ? *(const float4*)&Bm[(rbase+row)*8 + q*4]
                       : *(const float4*)&Cm[(rbase+row)*8 + (q-2)*4];
    *(float4*)&bc[row*16 + q*4] = v;
  }
  __syncthreads();
  // quad-scan: thread = (d, q in 0..3) handling states q*2, q*2+1
  {
    int d = tid >> 2, q = tid & 3;
    float2 av = *(const float2*)&A_log[d*8 + q*2];
    float a0 = -__expf(av.x), a1 = -__expf(av.y);
    float2 hv = *(const float2*)&hIn[(((size_t)cid)*128 + d)*8 + q*2];
    float h0 = hv.x, h1 = hv.y;
    float Dpd = Dp[d];
    #pragma unroll 4
    for (int r = 0; r < 64; ++r) {
      size_t rr = rbase + r;
      float dtv = dt[rr*DI_ + d];
      float xmv = xm[rr*DI_ + d];
      float zv  = z[rr*DI_ + d];
      float dx = dtv * xmv;
      float part = (q == 0) ? xmv * Dpd : 0.f;
      float e0 = __expf(dtv*a0), e1 = __expf(dtv*a1);
      h0 = e0*h0 + dx*bc[r*16 + q*2 + 0];
      h1 = e1*h1 + dx*bc[r*16 + q*2 + 1];
      part += h0*bc[r*16 + 8 + q*2 + 0];
      part += h1*bc[r*16 + 8 + q*2 + 1];
      part += __shfl_xor(part, 1, 64);
      part += __shfl_xor(part, 2, 64);
      if (q == 0) {
        float sg = 1.f / (1.f + __expf(-zv));
        y2t[r*129 + d] = part * zv * sg;
      }
    }
  }
  __syncthreads();
  // out[64x64] = y2t[64x128] @ Wo[128x64] + u   (2 rows per thread)
  int tx = tid & 15, ty = tid >> 4;   // ty 0..31
  int col = tx*4;
  float acc[2][4] = {};
  #pragma unroll 2
  for (int k = 0; k < 128; ++k) {
    float4 bv = *(const float4*)&Wo[(size_t)k*64 + col];
    #pragma unroll
    for (int i = 0; i < 2; ++i) {
      float a = y2t[(ty*2+i)*129 + k];
      acc[i][0] += a*bv.x; acc[i][1] += a*bv.y; acc[i][2] += a*bv.z; acc[i][3] += a*bv.w;
    }
  }
  #pragma unroll
  for (int i = 0; i < 2; ++i) {
    size_t row = rbase + ty*2 + i;
    float4 uv = *(const float4*)&u[row*64 + col];
    float4 o;
    o.x = uv.x + acc[i][0]; o.y = uv.y + acc[i][1]; o.z = uv.z + acc[i][2]; o.w = uv.w + acc[i][3];
    *(float4*)&out[row*64 + col] = o;
  }
}

// ---------------- launch ----------------
extern "C" void kernel_launch(void* const* d_in, const int* in_sizes, int n_in,
                              void* d_out, int out_size, void* d_ws, size_t ws_size,
                              hipStream_t stream) {
  const float* x        = (const float*)d_in[0];
  const float* mconv_w  = (const float*)d_in[1];
  const float* mconv_b  = (const float*)d_in[2];
  const float* mWq      = (const float*)d_in[3];
  const float* mMk      = (const float*)d_in[4];
  const float* mMv      = (const float*)d_in[5];
  const float* memWq    = (const float*)d_in[6];
  const float* memM     = (const float*)d_in[7];
  const float* memWo    = (const float*)d_in[8];
  const float* memWt    = (const float*)d_in[9];
  const float* ln_w     = (const float*)d_in[10];
  const float* ln_b     = (const float*)d_in[11];
  const float* in_proj  = (const float*)d_in[12];
  const float* conv1d_w = (const float*)d_in[13];
  const float* conv1d_b = (const float*)d_in[14];
  const float* x_proj   = (const float*)d_in[15];
  const float* dt_w     = (const float*)d_in[16];
  const float* dt_b     = (const float*)d_in[17];
  const float* A_log    = (const float*)d_in[18];
  const float* Dp       = (const float*)d_in[19];
  const float* out_proj = (const float*)d_in[20];
  float* out = (float*)d_out;
  float* ws  = (float*)d_ws;

  float* W1      = ws + 0;          // 640
  float* W1m     = ws + 640;        // 640
  float* W2m     = ws + 1280;       // 640
  float* conv_raw= ws + 2048;       // 1,310,720
  float* memo    = ws + 1312768;    // 4,456,448
  float* u       = ws + 5769216;    // 3,145,728
  float* z       = ws + 8914944;    // 6,291,456
  float* xm      = ws + 15206400;   // 6,291,456
  float* dt      = ws + 21497856;   // 6,291,456
  float* Bm      = ws + 27789312;   // 393,216
  float* Cm      = ws + 28182528;   // 393,216
  float* aggP    = ws + 28575744;   // 786,432
  float* aggS    = ws + 29362176;   // 786,432
  float* hIn     = ws + 30148608;   // 786,432

  hipLaunchKernelGGL(k0_precomp, dim3(1), dim3(64), 0, stream,
                     mWq, mMk, memWq, memM, memWo, W1, W1m, W2m);
  hipLaunchKernelGGL(k1a_conv, dim3(32, 5, 2), dim3(256), 0, stream,
                     x, mconv_w, mconv_b, conv_raw);
  hipLaunchKernelGGL(k2m, dim3(1088), dim3(256), 0, stream,
                     x, conv_raw, W1, mMv, W1m, W2m, memo);
  hipLaunchKernelGGL(k3_mix, dim3(1024), dim3(256), 0, stream,
                     x, memo, memWt, u);
  hipLaunchKernelGGL(f1_chunk, dim3(768), dim3(512), 0, stream,
                     u, ln_w, ln_b, in_proj, conv1d_w, conv1d_b,
                     x_proj, dt_w, dt_b, A_log,
                     xm, z, dt, Bm, Cm, aggP, aggS);
  hipLaunchKernelGGL(s2_scan_chunks, dim3(8), dim3(256), 0, stream,
                     aggP, aggS, hIn);
  hipLaunchKernelGGL(f3_scan_out, dim3(768), dim3(512), 0, stream,
                     dt, xm, z, Bm, Cm, hIn, A_log, Dp, out_proj, u, out);
}